// Round 1
// baseline (552.127 us; speedup 1.0000x reference)
//
#include <hip/hip_runtime.h>

// ---------- types ----------
typedef float f32x4 __attribute__((ext_vector_type(4)));
typedef __bf16 bf16x8 __attribute__((ext_vector_type(8)));
typedef short s16x8 __attribute__((ext_vector_type(8)));

// f32 -> bf16 round-to-nearest-even
__device__ __forceinline__ unsigned short f2bf(float f) {
  union { float f; unsigned u; } v;
  v.f = f;
  unsigned r = v.u + 0x7FFFu + ((v.u >> 16) & 1u);
  return (unsigned short)(r >> 16);
}

// async 16B global->LDS (wave-uniform base + lane*16; our mappings respect this)
__device__ __forceinline__ void gl_lds16(const void* g, void* l) {
  __builtin_amdgcn_global_load_lds(
      (__attribute__((address_space(1))) void*)g,
      (__attribute__((address_space(3))) void*)l, 16, 0, 0);
}

// ---------- pre-pass kernels ----------
__global__ __launch_bounds__(256) void k_convert_x(const float* __restrict__ in,
                                                   short* __restrict__ out) {
  int i = (blockIdx.x * 256 + threadIdx.x) * 8;
  const float4* p = (const float4*)(in + i);
  float4 a = p[0], b = p[1];
  s16x8 r;
  r[0] = (short)f2bf(a.x); r[1] = (short)f2bf(a.y);
  r[2] = (short)f2bf(a.z); r[3] = (short)f2bf(a.w);
  r[4] = (short)f2bf(b.x); r[5] = (short)f2bf(b.y);
  r[6] = (short)f2bf(b.z); r[7] = (short)f2bf(b.w);
  *(s16x8*)(out + i) = r;
}

// in: [R,C] f32 row-major -> out: [C,R] bf16 row-major
__global__ __launch_bounds__(256) void k_transpose_cvt(const float* __restrict__ in,
                                                       short* __restrict__ out,
                                                       int R, int C) {
  __shared__ short tile[32][33];
  int c0 = blockIdx.x * 32, r0 = blockIdx.y * 32;
  int tx = threadIdx.x, ty = threadIdx.y;
#pragma unroll
  for (int i = 0; i < 32; i += 8)
    tile[ty + i][tx] = (short)f2bf(in[(size_t)(r0 + ty + i) * C + c0 + tx]);
  __syncthreads();
#pragma unroll
  for (int i = 0; i < 32; i += 8)
    out[(size_t)(c0 + ty + i) * R + r0 + tx] = tile[tx][ty + i];
}

// ---------- QKV GEMM: C[8192,3072] = Xbf[8192,1024] @ WinT[3072,1024]^T + b ----------
// epilogue scatters: Q,K -> [B,H,L,64] bf16 ; V -> Vt [B,H,64,L] bf16
__global__ __launch_bounds__(256) void k_qkv_gemm(const short* __restrict__ A,
                                                  const short* __restrict__ B,
                                                  const float* __restrict__ bias,
                                                  short* __restrict__ qb,
                                                  short* __restrict__ kb,
                                                  short* __restrict__ vtb) {
  __shared__ short As[128 * 32];
  __shared__ short Bs[128 * 32];
  const int tid = threadIdx.x;
  const int lane = tid & 63;
  const int w = tid >> 6;
  const int g = lane >> 4, c = lane & 15;
  const int m0 = blockIdx.y * 128, n0 = blockIdx.x * 128;
  const int wm = (w >> 1) * 64, wn = (w & 1) * 64;
  f32x4 acc[4][4] = {};
  const int p0 = tid, p1 = tid + 256;
  const int rowA0 = p0 >> 2, logA0 = (p0 & 3) ^ ((p0 >> 3) & 3);
  const int rowA1 = p1 >> 2, logA1 = (p1 & 3) ^ ((p1 >> 3) & 3);
  const short* a0 = A + (size_t)(m0 + rowA0) * 1024 + logA0 * 8;
  const short* a1 = A + (size_t)(m0 + rowA1) * 1024 + logA1 * 8;
  const short* b0 = B + (size_t)(n0 + rowA0) * 1024 + logA0 * 8;
  const short* b1 = B + (size_t)(n0 + rowA1) * 1024 + logA1 * 8;
  short* lA0 = As + p0 * 8; short* lA1 = As + p1 * 8;
  short* lB0 = Bs + p0 * 8; short* lB1 = Bs + p1 * 8;

  for (int k0 = 0; k0 < 1024; k0 += 32) {
    gl_lds16(a0 + k0, lA0);
    gl_lds16(a1 + k0, lA1);
    gl_lds16(b0 + k0, lB0);
    gl_lds16(b1 + k0, lB1);
    __syncthreads();
    bf16x8 af[4], bfr[4];
#pragma unroll
    for (int t = 0; t < 4; t++) {
      int ra = wm + t * 16 + c;
      af[t] = *(const bf16x8*)(As + ra * 32 + (g ^ ((ra >> 1) & 3)) * 8);
      int rb = wn + t * 16 + c;
      bfr[t] = *(const bf16x8*)(Bs + rb * 32 + (g ^ ((rb >> 1) & 3)) * 8);
    }
#pragma unroll
    for (int i = 0; i < 4; i++)
#pragma unroll
      for (int jn = 0; jn < 4; jn++)
        acc[i][jn] = __builtin_amdgcn_mfma_f32_16x16x32_bf16(af[i], bfr[jn], acc[i][jn], 0, 0, 0);
    __syncthreads();
  }

  const int which = n0 >> 10;  // block-uniform: 0=Q 1=K 2=V
#pragma unroll
  for (int jn = 0; jn < 4; jn++) {
    const int col = n0 + wn + jn * 16 + c;
    const float bv = bias[col];
    const int cw = col & 1023;
    const int h = cw >> 6, d = cw & 63;
#pragma unroll
    for (int i = 0; i < 4; i++) {
#pragma unroll
      for (int r = 0; r < 4; r++) {
        const int row = m0 + wm + i * 16 + g * 4 + r;
        const int bb = row >> 11, l = row & 2047;
        const short ov = (short)f2bf(acc[i][jn][r] + bv);
        if (which == 0)
          qb[((size_t)((bb * 16 + h) * 2048 + l) << 6) + d] = ov;
        else if (which == 1)
          kb[((size_t)((bb * 16 + h) * 2048 + l) << 6) + d] = ov;
        else
          vtb[(size_t)((bb * 16 + h) * 64 + d) * 2048 + l] = ov;
      }
    }
  }
}

// ---------- flash attention: 1 block = (bh, 128-query tile) ----------
__global__ __launch_bounds__(256) void k_attn(const short* __restrict__ Q,
                                              const short* __restrict__ K,
                                              const short* __restrict__ Vt,
                                              short* __restrict__ O) {
  __shared__ short Ks[128 * 64];    // 16 KB, keys x dim, 8-chunk XOR swizzle
  __shared__ short Vs[64 * 128];    // 16 KB, dim x keys (V^T), 16-chunk XOR swizzle
  __shared__ short Ps[4 * 32 * 128];// 32 KB, first Q staging, then per-wave P
  const int tid = threadIdx.x;
  const int lane = tid & 63;
  const int w = tid >> 6;
  const int g = lane >> 4, c = lane & 15;
  const int qt = blockIdx.x, bh = blockIdx.y;
  const int m0 = qt * 128;
  const size_t base = (size_t)bh * (2048 * 64);

  // stage Q tile (128x64) into Ps front half
#pragma unroll
  for (int t = 0; t < 4; t++) {
    int p = tid + t * 256;
    int row = p >> 3, logi = (p & 7) ^ (row & 7);
    gl_lds16(Q + base + (size_t)(m0 + row) * 64 + logi * 8, Ps + p * 8);
  }
  __syncthreads();
  bf16x8 qf[2][2];  // Q A-frags, kept in regs for whole kernel
#pragma unroll
  for (int mt = 0; mt < 2; mt++)
#pragma unroll
    for (int kd = 0; kd < 2; kd++) {
      int row = w * 32 + mt * 16 + c;
      int phys = (kd * 4 + g) ^ (row & 7);
      qf[mt][kd] = *(const bf16x8*)(Ps + row * 64 + phys * 8);
    }
  __syncthreads();  // everyone done with Q region before P overwrites it

  f32x4 o[2][4] = {};
  float m_run[2][4], l_run[2][4];
#pragma unroll
  for (int mt = 0; mt < 2; mt++)
#pragma unroll
    for (int r = 0; r < 4; r++) { m_run[mt][r] = -1e30f; l_run[mt][r] = 0.f; }
  const float sl2e = 0.125f * 1.4426950408889634f;  // scale * log2(e)
  short* myP = Ps + w * 4096;

  for (int j = 0; j <= qt; j++) {
    // stage K (128x64) and V^T (64x128) tiles
#pragma unroll
    for (int t = 0; t < 4; t++) {
      int p = tid + t * 256;
      int row = p >> 3, logi = (p & 7) ^ (row & 7);
      gl_lds16(K + base + (size_t)(j * 128 + row) * 64 + logi * 8, Ks + p * 8);
      int dv = p >> 4, logv = (p & 15) ^ (dv & 15);
      gl_lds16(Vt + base + (size_t)dv * 2048 + j * 128 + logv * 8, Vs + p * 8);
    }
    __syncthreads();

    // S = Q K^T (wave: 32 queries x 128 keys)
    f32x4 s[2][8] = {};
#pragma unroll
    for (int kd = 0; kd < 2; kd++) {
#pragma unroll
      for (int nt = 0; nt < 8; nt++) {
        int row = nt * 16 + c;
        int phys = (kd * 4 + g) ^ (row & 7);
        bf16x8 kf = *(const bf16x8*)(Ks + row * 64 + phys * 8);
        s[0][nt] = __builtin_amdgcn_mfma_f32_16x16x32_bf16(qf[0][kd], kf, s[0][nt], 0, 0, 0);
        s[1][nt] = __builtin_amdgcn_mfma_f32_16x16x32_bf16(qf[1][kd], kf, s[1][nt], 0, 0, 0);
      }
    }

    const bool diag = (j == qt);
#pragma unroll
    for (int mt = 0; mt < 2; mt++) {
      float mx[4];
#pragma unroll
      for (int r = 0; r < 4; r++) mx[r] = -1e30f;
#pragma unroll
      for (int nt = 0; nt < 8; nt++)
#pragma unroll
        for (int r = 0; r < 4; r++) {
          float v = s[mt][nt][r] * sl2e;
          if (diag && (nt * 16 + c) > (w * 32 + mt * 16 + g * 4 + r)) v = -1e30f;
          s[mt][nt][r] = v;
          mx[r] = fmaxf(mx[r], v);
        }
#pragma unroll
      for (int r = 0; r < 4; r++) {
        float v = mx[r];
        v = fmaxf(v, __shfl_xor(v, 1));
        v = fmaxf(v, __shfl_xor(v, 2));
        v = fmaxf(v, __shfl_xor(v, 4));
        v = fmaxf(v, __shfl_xor(v, 8));
        mx[r] = v;
      }
      float alpha[4], lt[4];
#pragma unroll
      for (int r = 0; r < 4; r++) {
        float mn = fmaxf(m_run[mt][r], mx[r]);
        alpha[r] = exp2f(m_run[mt][r] - mn);
        m_run[mt][r] = mn;
        lt[r] = 0.f;
      }
#pragma unroll
      for (int nt = 0; nt < 8; nt++)
#pragma unroll
        for (int r = 0; r < 4; r++) {
          float pval = exp2f(s[mt][nt][r] - m_run[mt][r]);
          lt[r] += pval;
          int rowl = mt * 16 + g * 4 + r;
          int n = nt * 16 + c;
          int phys = (n >> 3) ^ (rowl & 15);
          myP[rowl * 128 + phys * 8 + (n & 7)] = (short)f2bf(pval);
        }
#pragma unroll
      for (int r = 0; r < 4; r++) {
        float v = lt[r];
        v += __shfl_xor(v, 1);
        v += __shfl_xor(v, 2);
        v += __shfl_xor(v, 4);
        v += __shfl_xor(v, 8);
        l_run[mt][r] = l_run[mt][r] * alpha[r] + v;
#pragma unroll
        for (int dn = 0; dn < 4; dn++) o[mt][dn][r] *= alpha[r];
      }
    }

    // O += P V  (P wave-private in LDS; no barrier needed, lgkmcnt handles RAW)
#pragma unroll
    for (int kt = 0; kt < 4; kt++) {
      bf16x8 pf[2];
#pragma unroll
      for (int mt = 0; mt < 2; mt++) {
        int rowl = mt * 16 + c;
        int phys = (kt * 4 + g) ^ (rowl & 15);
        pf[mt] = *(const bf16x8*)(myP + rowl * 128 + phys * 8);
      }
#pragma unroll
      for (int dn = 0; dn < 4; dn++) {
        int dd = dn * 16 + c;
        int phys = (kt * 4 + g) ^ (dd & 15);
        bf16x8 vf = *(const bf16x8*)(Vs + dd * 128 + phys * 8);
        o[0][dn] = __builtin_amdgcn_mfma_f32_16x16x32_bf16(pf[0], vf, o[0][dn], 0, 0, 0);
        o[1][dn] = __builtin_amdgcn_mfma_f32_16x16x32_bf16(pf[1], vf, o[1][dn], 0, 0, 0);
      }
    }
    __syncthreads();
  }

  // epilogue: normalize, write [B,L,H,Hd] bf16
  const int bb = bh >> 4, h = bh & 15;
#pragma unroll
  for (int mt = 0; mt < 2; mt++) {
#pragma unroll
    for (int r = 0; r < 4; r++) {
      float inv = 1.f / l_run[mt][r];
      int q = m0 + w * 32 + mt * 16 + g * 4 + r;
      size_t rowbase = ((size_t)bb * 2048 + q) * 1024 + h * 64;
#pragma unroll
      for (int dn = 0; dn < 4; dn++)
        O[rowbase + dn * 16 + c] = (short)f2bf(o[mt][dn][r] * inv);
    }
  }
}

// ---------- out GEMM: out[8192,1024] = AO[8192,1024] @ WoutT[1024,1024]^T + b (fp32 out) ----------
__global__ __launch_bounds__(256) void k_out_gemm(const short* __restrict__ A,
                                                  const short* __restrict__ B,
                                                  const float* __restrict__ bias,
                                                  float* __restrict__ out) {
  __shared__ short As[128 * 32];
  __shared__ short Bs[128 * 32];
  const int tid = threadIdx.x;
  const int lane = tid & 63;
  const int w = tid >> 6;
  const int g = lane >> 4, c = lane & 15;
  const int m0 = blockIdx.y * 128, n0 = blockIdx.x * 128;
  const int wm = (w >> 1) * 64, wn = (w & 1) * 64;
  f32x4 acc[4][4] = {};
  const int p0 = tid, p1 = tid + 256;
  const int rowA0 = p0 >> 2, logA0 = (p0 & 3) ^ ((p0 >> 3) & 3);
  const int rowA1 = p1 >> 2, logA1 = (p1 & 3) ^ ((p1 >> 3) & 3);
  const short* a0 = A + (size_t)(m0 + rowA0) * 1024 + logA0 * 8;
  const short* a1 = A + (size_t)(m0 + rowA1) * 1024 + logA1 * 8;
  const short* b0 = B + (size_t)(n0 + rowA0) * 1024 + logA0 * 8;
  const short* b1 = B + (size_t)(n0 + rowA1) * 1024 + logA1 * 8;
  short* lA0 = As + p0 * 8; short* lA1 = As + p1 * 8;
  short* lB0 = Bs + p0 * 8; short* lB1 = Bs + p1 * 8;

  for (int k0 = 0; k0 < 1024; k0 += 32) {
    gl_lds16(a0 + k0, lA0);
    gl_lds16(a1 + k0, lA1);
    gl_lds16(b0 + k0, lB0);
    gl_lds16(b1 + k0, lB1);
    __syncthreads();
    bf16x8 af[4], bfr[4];
#pragma unroll
    for (int t = 0; t < 4; t++) {
      int ra = wm + t * 16 + c;
      af[t] = *(const bf16x8*)(As + ra * 32 + (g ^ ((ra >> 1) & 3)) * 8);
      int rb = wn + t * 16 + c;
      bfr[t] = *(const bf16x8*)(Bs + rb * 32 + (g ^ ((rb >> 1) & 3)) * 8);
    }
#pragma unroll
    for (int i = 0; i < 4; i++)
#pragma unroll
      for (int jn = 0; jn < 4; jn++)
        acc[i][jn] = __builtin_amdgcn_mfma_f32_16x16x32_bf16(af[i], bfr[jn], acc[i][jn], 0, 0, 0);
    __syncthreads();
  }
#pragma unroll
  for (int jn = 0; jn < 4; jn++) {
    const int col = n0 + wn + jn * 16 + c;
    const float bv = bias[col];
#pragma unroll
    for (int i = 0; i < 4; i++) {
#pragma unroll
      for (int r = 0; r < 4; r++) {
        const int row = m0 + wm + i * 16 + g * 4 + r;
        out[(size_t)row * 1024 + col] = acc[i][jn][r] + bv;
      }
    }
  }
}

// ---------- launch ----------
extern "C" void kernel_launch(void* const* d_in, const int* in_sizes, int n_in,
                              void* d_out, int out_size, void* d_ws, size_t ws_size,
                              hipStream_t stream) {
  const float* x     = (const float*)d_in[0];
  const float* w_in  = (const float*)d_in[1];
  const float* b_in  = (const float*)d_in[2];
  const float* w_out = (const float*)d_in[3];
  const float* b_out = (const float*)d_in[4];
  float* out = (float*)d_out;
  char* ws = (char*)d_ws;
  // workspace layout (needs 88 MB)
  short* x_bf   = (short*)(ws);                      // 16 MB  [8192,1024] bf16
  short* w_inT  = (short*)(ws + (16ull << 20));      //  6 MB  [3072,1024] bf16
  short* w_outT = (short*)(ws + (22ull << 20));      //  2 MB  [1024,1024] bf16
  short* qb     = (short*)(ws + (24ull << 20));      // 16 MB  [B,H,L,64]  bf16
  short* kb     = (short*)(ws + (40ull << 20));      // 16 MB  [B,H,L,64]  bf16
  short* vtb    = (short*)(ws + (56ull << 20));      // 16 MB  [B,H,64,L]  bf16
  short* ao     = (short*)(ws + (72ull << 20));      // 16 MB  [B,L,H*64]  bf16

  k_convert_x<<<dim3(4096), dim3(256), 0, stream>>>(x, x_bf);
  k_transpose_cvt<<<dim3(96, 32), dim3(32, 8), 0, stream>>>(w_in, w_inT, 1024, 3072);
  k_transpose_cvt<<<dim3(32, 32), dim3(32, 8), 0, stream>>>(w_out, w_outT, 1024, 1024);
  k_qkv_gemm<<<dim3(24, 64), dim3(256), 0, stream>>>(x_bf, w_inT, b_in, qb, kb, vtb);
  k_attn<<<dim3(16, 64), dim3(256), 0, stream>>>(qb, kb, vtb, ao);
  k_out_gemm<<<dim3(8, 64), dim3(256), 0, stream>>>(ao, w_outT, b_out, out);
}

// Round 2
// 328.102 us; speedup vs baseline: 1.6828x; 1.6828x over previous
//
#include <hip/hip_runtime.h>

// ---------- types ----------
typedef float f32x4 __attribute__((ext_vector_type(4)));
typedef __bf16 bf16x8 __attribute__((ext_vector_type(8)));
typedef short s16x8 __attribute__((ext_vector_type(8)));
typedef int i32x4 __attribute__((ext_vector_type(4)));

// f32 -> bf16 round-to-nearest-even
__device__ __forceinline__ unsigned short f2bf(float f) {
  union { float f; unsigned u; } v;
  v.f = f;
  unsigned r = v.u + 0x7FFFu + ((v.u >> 16) & 1u);
  return (unsigned short)(r >> 16);
}

// pack two f32 -> packed bf16x2 (round-half-up via +0x8000, then byte-perm)
__device__ __forceinline__ int pk2bf(float lo, float hi) {
  unsigned a = __builtin_bit_cast(unsigned, lo) + 0x8000u;
  unsigned b = __builtin_bit_cast(unsigned, hi) + 0x8000u;
  return (int)__builtin_amdgcn_perm(b, a, 0x07060302u);
}

#if __has_builtin(__builtin_amdgcn_exp2f)
__device__ __forceinline__ float fexp2(float x) { return __builtin_amdgcn_exp2f(x); }
#else
__device__ __forceinline__ float fexp2(float x) { return exp2f(x); }
#endif

// async 16B global->LDS (wave-uniform base + lane*16; our mappings respect this)
__device__ __forceinline__ void gl_lds16(const void* g, void* l) {
  __builtin_amdgcn_global_load_lds(
      (__attribute__((address_space(1))) void*)g,
      (__attribute__((address_space(3))) void*)l, 16, 0, 0);
}

// ---------- pre-pass kernels ----------
__global__ __launch_bounds__(256) void k_convert_x(const float* __restrict__ in,
                                                   short* __restrict__ out) {
  int i = (blockIdx.x * 256 + threadIdx.x) * 8;
  const float4* p = (const float4*)(in + i);
  float4 a = p[0], b = p[1];
  s16x8 r;
  r[0] = (short)f2bf(a.x); r[1] = (short)f2bf(a.y);
  r[2] = (short)f2bf(a.z); r[3] = (short)f2bf(a.w);
  r[4] = (short)f2bf(b.x); r[5] = (short)f2bf(b.y);
  r[6] = (short)f2bf(b.z); r[7] = (short)f2bf(b.w);
  *(s16x8*)(out + i) = r;
}

// in: [R,C] f32 row-major -> out: [C,R] bf16 row-major
__global__ __launch_bounds__(256) void k_transpose_cvt(const float* __restrict__ in,
                                                       short* __restrict__ out,
                                                       int R, int C) {
  __shared__ short tile[32][33];
  int c0 = blockIdx.x * 32, r0 = blockIdx.y * 32;
  int tx = threadIdx.x, ty = threadIdx.y;
#pragma unroll
  for (int i = 0; i < 32; i += 8)
    tile[ty + i][tx] = (short)f2bf(in[(size_t)(r0 + ty + i) * C + c0 + tx]);
  __syncthreads();
#pragma unroll
  for (int i = 0; i < 32; i += 8)
    out[(size_t)(c0 + ty + i) * R + r0 + tx] = tile[tx][ty + i];
}

// ---------- QKV GEMM: C[8192,3072] = Xbf[8192,1024] @ WinT[3072,1024]^T + b ----------
// epilogue scatters: Q (pre-scaled by scale*log2e), K -> [B,H,L,64] bf16 ; V -> Vt [B,H,64,L] bf16
__global__ __launch_bounds__(256) void k_qkv_gemm(const short* __restrict__ A,
                                                  const short* __restrict__ B,
                                                  const float* __restrict__ bias,
                                                  short* __restrict__ qb,
                                                  short* __restrict__ kb,
                                                  short* __restrict__ vtb) {
  __shared__ short As[128 * 32];
  __shared__ short Bs[128 * 32];
  const int tid = threadIdx.x;
  const int lane = tid & 63;
  const int w = tid >> 6;
  const int g = lane >> 4, c = lane & 15;
  const int m0 = blockIdx.y * 128, n0 = blockIdx.x * 128;
  const int wm = (w >> 1) * 64, wn = (w & 1) * 64;
  f32x4 acc[4][4] = {};
  const int p0 = tid, p1 = tid + 256;
  const int rowA0 = p0 >> 2, logA0 = (p0 & 3) ^ ((p0 >> 3) & 3);
  const int rowA1 = p1 >> 2, logA1 = (p1 & 3) ^ ((p1 >> 3) & 3);
  const short* a0 = A + (size_t)(m0 + rowA0) * 1024 + logA0 * 8;
  const short* a1 = A + (size_t)(m0 + rowA1) * 1024 + logA1 * 8;
  const short* b0 = B + (size_t)(n0 + rowA0) * 1024 + logA0 * 8;
  const short* b1 = B + (size_t)(n0 + rowA1) * 1024 + logA1 * 8;
  short* lA0 = As + p0 * 8; short* lA1 = As + p1 * 8;
  short* lB0 = Bs + p0 * 8; short* lB1 = Bs + p1 * 8;

  for (int k0 = 0; k0 < 1024; k0 += 32) {
    gl_lds16(a0 + k0, lA0);
    gl_lds16(a1 + k0, lA1);
    gl_lds16(b0 + k0, lB0);
    gl_lds16(b1 + k0, lB1);
    __syncthreads();
    bf16x8 af[4], bfr[4];
#pragma unroll
    for (int t = 0; t < 4; t++) {
      int ra = wm + t * 16 + c;
      af[t] = *(const bf16x8*)(As + ra * 32 + (g ^ ((ra >> 1) & 3)) * 8);
      int rb = wn + t * 16 + c;
      bfr[t] = *(const bf16x8*)(Bs + rb * 32 + (g ^ ((rb >> 1) & 3)) * 8);
    }
#pragma unroll
    for (int i = 0; i < 4; i++)
#pragma unroll
      for (int jn = 0; jn < 4; jn++)
        acc[i][jn] = __builtin_amdgcn_mfma_f32_16x16x32_bf16(af[i], bfr[jn], acc[i][jn], 0, 0, 0);
    __syncthreads();
  }

  const int which = n0 >> 10;  // block-uniform: 0=Q 1=K 2=V
  const float qscale = 0.125f * 1.4426950408889634f;  // folded into Q
#pragma unroll
  for (int jn = 0; jn < 4; jn++) {
    const int col = n0 + wn + jn * 16 + c;
    const float bv = bias[col];
    const int cw = col & 1023;
    const int h = cw >> 6, d = cw & 63;
#pragma unroll
    for (int i = 0; i < 4; i++) {
#pragma unroll
      for (int r = 0; r < 4; r++) {
        const int row = m0 + wm + i * 16 + g * 4 + r;
        const int bb = row >> 11, l = row & 2047;
        float val = acc[i][jn][r] + bv;
        if (which == 0) {
          qb[((size_t)((bb * 16 + h) * 2048 + l) << 6) + d] = (short)f2bf(val * qscale);
        } else if (which == 1) {
          kb[((size_t)((bb * 16 + h) * 2048 + l) << 6) + d] = (short)f2bf(val);
        } else {
          vtb[(size_t)((bb * 16 + h) * 64 + d) * 2048 + l] = (short)f2bf(val);
        }
      }
    }
  }
}

// ---------- flash attention (S^T form): 1 block = (bh, paired 128-query tiles) ----------
// S^T = mfma(Kfrag, Qfrag) -> col=q, row=key. Softmax stats per column (2 shuffles).
// P^T -> PV B-frag via quad-routing ds_bpermute (no LDS round trip).
// O^T = mfma(Vtfrag, Pfrag) -> col=q, row=d; packed 8B stores to [B,L,H*64].
__global__ __launch_bounds__(256, 3) void k_attn(const short* __restrict__ Q,
                                                 const short* __restrict__ K,
                                                 const short* __restrict__ Vt,
                                                 short* __restrict__ O) {
  __shared__ short Ks[128 * 64];  // 16 KB [key][d], 8-chunk XOR swizzle
  __shared__ short Vs[64 * 128];  // 16 KB [d][key], 16-chunk XOR swizzle
  const int tid = threadIdx.x;
  const int lane = tid & 63;
  const int w = tid >> 6;
  const int quad = lane >> 4, cq = lane & 15;
  const int bh = blockIdx.y;
  const int bb = bh >> 4, h = bh & 15;
  const size_t base = (size_t)bh * (2048 * 64);
  const int pr = blockIdx.x;  // 0..7 ; pair (15-pr, pr): 17 KV tiles per block
  // bpermute source lanes for P^T -> B-frag quad routing (tile-invariant)
  const int sA = cq | (((2 * quad) & 3) << 4);
  const int sB = cq | (((2 * quad + 1) & 3) << 4);

  for (int phase = 0; phase < 2; phase++) {
    const int qt = phase ? pr : 15 - pr;
    const int m0 = qt * 128;
    // Q B-frags straight from global (16B/lane, 64B-contiguous per row)
    bf16x8 qf[2][2];
#pragma unroll
    for (int mt = 0; mt < 2; mt++)
#pragma unroll
      for (int kd = 0; kd < 2; kd++)
        qf[mt][kd] = *(const bf16x8*)(Q + base +
            (size_t)(m0 + w * 32 + mt * 16 + cq) * 64 + (kd * 4 + quad) * 8);

    f32x4 o[2][4] = {};
    float m_run[2] = {-1e30f, -1e30f};
    float l_run[2] = {0.f, 0.f};  // per-lane partial (reduced across quads at end)

    for (int j = 0; j <= qt; j++) {
      __syncthreads();  // previous tile fully consumed
#pragma unroll
      for (int t = 0; t < 4; t++) {
        int p = tid + t * 256;
        int krow = p >> 3, kchk = (p & 7) ^ (krow & 7);
        gl_lds16(K + base + (size_t)(j * 128 + krow) * 64 + kchk * 8, Ks + p * 8);
        int dv = p >> 4, vchk = (p & 15) ^ (dv & 15);
        gl_lds16(Vt + base + (size_t)dv * 2048 + j * 128 + vchk * 8, Vs + p * 8);
      }
      __syncthreads();

      // S^T[key][q] : per wave 128 keys x 32 queries
      f32x4 s[2][8] = {};
#pragma unroll
      for (int kd = 0; kd < 2; kd++)
#pragma unroll
        for (int nt = 0; nt < 8; nt++) {
          int krow = nt * 16 + cq;
          bf16x8 kf = *(const bf16x8*)(Ks + krow * 64 + ((kd * 4 + quad) ^ (krow & 7)) * 8);
          s[0][nt] = __builtin_amdgcn_mfma_f32_16x16x32_bf16(kf, qf[0][kd], s[0][nt], 0, 0, 0);
          s[1][nt] = __builtin_amdgcn_mfma_f32_16x16x32_bf16(kf, qf[1][kd], s[1][nt], 0, 0, 0);
        }

      const bool diag = (j == qt);
      bf16x8 pf[2][4];
#pragma unroll
      for (int mt = 0; mt < 2; mt++) {
        float mx = -1e30f;
        if (diag) {
          int qloc = w * 32 + mt * 16 + cq;
#pragma unroll
          for (int nt = 0; nt < 8; nt++)
#pragma unroll
            for (int r = 0; r < 4; r++) {
              float v = (nt * 16 + quad * 4 + r > qloc) ? -1e30f : s[mt][nt][r];
              s[mt][nt][r] = v;
              mx = fmaxf(mx, v);
            }
        } else {
#pragma unroll
          for (int nt = 0; nt < 8; nt++)
#pragma unroll
            for (int r = 0; r < 4; r++) mx = fmaxf(mx, s[mt][nt][r]);
        }
        mx = fmaxf(mx, __shfl_xor(mx, 16));
        mx = fmaxf(mx, __shfl_xor(mx, 32));
        const float mn = fmaxf(m_run[mt], mx);
        const float alpha = fexp2(m_run[mt] - mn);
        m_run[mt] = mn;
        float lt = 0.f;
#pragma unroll
        for (int nt = 0; nt < 8; nt++)
#pragma unroll
          for (int r = 0; r < 4; r++) {
            float p = fexp2(s[mt][nt][r] - mn);
            s[mt][nt][r] = p;
            lt += p;
          }
        l_run[mt] = l_run[mt] * alpha + lt;
#pragma unroll
        for (int dn = 0; dn < 4; dn++) o[mt][dn] *= alpha;
        // P^T (C-layout) -> PV B-frag: pack pairs, route across quads
#pragma unroll
        for (int kt = 0; kt < 4; kt++) {
          int dA0 = pk2bf(s[mt][2 * kt][0], s[mt][2 * kt][1]);
          int dA1 = pk2bf(s[mt][2 * kt][2], s[mt][2 * kt][3]);
          int dB0 = pk2bf(s[mt][2 * kt + 1][0], s[mt][2 * kt + 1][1]);
          int dB1 = pk2bf(s[mt][2 * kt + 1][2], s[mt][2 * kt + 1][3]);
          i32x4 ow;
          {
            int t0 = __shfl(dA0, sA, 64), t1 = __shfl(dB0, sA, 64);
            ow[0] = (quad < 2) ? t0 : t1;
          }
          {
            int t0 = __shfl(dA1, sA, 64), t1 = __shfl(dB1, sA, 64);
            ow[1] = (quad < 2) ? t0 : t1;
          }
          {
            int t0 = __shfl(dA0, sB, 64), t1 = __shfl(dB0, sB, 64);
            ow[2] = (quad < 2) ? t0 : t1;
          }
          {
            int t0 = __shfl(dA1, sB, 64), t1 = __shfl(dB1, sB, 64);
            ow[3] = (quad < 2) ? t0 : t1;
          }
          pf[mt][kt] = __builtin_bit_cast(bf16x8, ow);
        }
      }

      // O^T += Vt * P  (A=Vt frag, B=P frag)
#pragma unroll
      for (int kt = 0; kt < 4; kt++)
#pragma unroll
        for (int dn = 0; dn < 4; dn++) {
          int drow = dn * 16 + cq;
          bf16x8 vtf = *(const bf16x8*)(Vs + drow * 128 + ((kt * 4 + quad) ^ (drow & 15)) * 8);
          o[0][dn] = __builtin_amdgcn_mfma_f32_16x16x32_bf16(vtf, pf[0][kt], o[0][dn], 0, 0, 0);
          o[1][dn] = __builtin_amdgcn_mfma_f32_16x16x32_bf16(vtf, pf[1][kt], o[1][dn], 0, 0, 0);
        }
    }

    // epilogue: reduce l across quads, normalize, pack 4 consecutive d -> 8B store
#pragma unroll
    for (int mt = 0; mt < 2; mt++) {
      float lf = l_run[mt];
      lf += __shfl_xor(lf, 16);
      lf += __shfl_xor(lf, 32);
      const float inv = 1.f / lf;
      const size_t rb = ((size_t)(bb * 2048 + m0 + w * 32 + mt * 16 + cq)) * 1024 + h * 64;
#pragma unroll
      for (int dn = 0; dn < 4; dn++) {
        int d0 = pk2bf(o[mt][dn][0] * inv, o[mt][dn][1] * inv);
        int d1 = pk2bf(o[mt][dn][2] * inv, o[mt][dn][3] * inv);
        *(int2*)(O + rb + dn * 16 + quad * 4) = make_int2(d0, d1);
      }
    }
  }
}

// ---------- out GEMM: out[8192,1024] = AO[8192,1024] @ WoutT[1024,1024]^T + b (fp32 out) ----------
__global__ __launch_bounds__(256) void k_out_gemm(const short* __restrict__ A,
                                                  const short* __restrict__ B,
                                                  const float* __restrict__ bias,
                                                  float* __restrict__ out) {
  __shared__ short As[128 * 32];
  __shared__ short Bs[128 * 32];
  const int tid = threadIdx.x;
  const int lane = tid & 63;
  const int w = tid >> 6;
  const int g = lane >> 4, c = lane & 15;
  const int m0 = blockIdx.y * 128, n0 = blockIdx.x * 128;
  const int wm = (w >> 1) * 64, wn = (w & 1) * 64;
  f32x4 acc[4][4] = {};
  const int p0 = tid, p1 = tid + 256;
  const int rowA0 = p0 >> 2, logA0 = (p0 & 3) ^ ((p0 >> 3) & 3);
  const int rowA1 = p1 >> 2, logA1 = (p1 & 3) ^ ((p1 >> 3) & 3);
  const short* a0 = A + (size_t)(m0 + rowA0) * 1024 + logA0 * 8;
  const short* a1 = A + (size_t)(m0 + rowA1) * 1024 + logA1 * 8;
  const short* b0 = B + (size_t)(n0 + rowA0) * 1024 + logA0 * 8;
  const short* b1 = B + (size_t)(n0 + rowA1) * 1024 + logA1 * 8;
  short* lA0 = As + p0 * 8; short* lA1 = As + p1 * 8;
  short* lB0 = Bs + p0 * 8; short* lB1 = Bs + p1 * 8;

  for (int k0 = 0; k0 < 1024; k0 += 32) {
    gl_lds16(a0 + k0, lA0);
    gl_lds16(a1 + k0, lA1);
    gl_lds16(b0 + k0, lB0);
    gl_lds16(b1 + k0, lB1);
    __syncthreads();
    bf16x8 af[4], bfr[4];
#pragma unroll
    for (int t = 0; t < 4; t++) {
      int ra = wm + t * 16 + c;
      af[t] = *(const bf16x8*)(As + ra * 32 + (g ^ ((ra >> 1) & 3)) * 8);
      int rb = wn + t * 16 + c;
      bfr[t] = *(const bf16x8*)(Bs + rb * 32 + (g ^ ((rb >> 1) & 3)) * 8);
    }
#pragma unroll
    for (int i = 0; i < 4; i++)
#pragma unroll
      for (int jn = 0; jn < 4; jn++)
        acc[i][jn] = __builtin_amdgcn_mfma_f32_16x16x32_bf16(af[i], bfr[jn], acc[i][jn], 0, 0, 0);
    __syncthreads();
  }
#pragma unroll
  for (int jn = 0; jn < 4; jn++) {
    const int col = n0 + wn + jn * 16 + c;
    const float bv = bias[col];
#pragma unroll
    for (int i = 0; i < 4; i++) {
#pragma unroll
      for (int r = 0; r < 4; r++) {
        const int row = m0 + wm + i * 16 + g * 4 + r;
        out[(size_t)row * 1024 + col] = acc[i][jn][r] + bv;
      }
    }
  }
}

// ---------- launch ----------
extern "C" void kernel_launch(void* const* d_in, const int* in_sizes, int n_in,
                              void* d_out, int out_size, void* d_ws, size_t ws_size,
                              hipStream_t stream) {
  const float* x     = (const float*)d_in[0];
  const float* w_in  = (const float*)d_in[1];
  const float* b_in  = (const float*)d_in[2];
  const float* w_out = (const float*)d_in[3];
  const float* b_out = (const float*)d_in[4];
  float* out = (float*)d_out;
  char* ws = (char*)d_ws;
  // workspace layout (needs 88 MB)
  short* x_bf   = (short*)(ws);                      // 16 MB  [8192,1024] bf16
  short* w_inT  = (short*)(ws + (16ull << 20));      //  6 MB  [3072,1024] bf16
  short* w_outT = (short*)(ws + (22ull << 20));      //  2 MB  [1024,1024] bf16
  short* qb     = (short*)(ws + (24ull << 20));      // 16 MB  [B,H,L,64]  bf16 (pre-scaled)
  short* kb     = (short*)(ws + (40ull << 20));      // 16 MB  [B,H,L,64]  bf16
  short* vtb    = (short*)(ws + (56ull << 20));      // 16 MB  [B,H,64,L]  bf16
  short* ao     = (short*)(ws + (72ull << 20));      // 16 MB  [B,L,H*64]  bf16

  k_convert_x<<<dim3(4096), dim3(256), 0, stream>>>(x, x_bf);
  k_transpose_cvt<<<dim3(96, 32), dim3(32, 8), 0, stream>>>(w_in, w_inT, 1024, 3072);
  k_transpose_cvt<<<dim3(32, 32), dim3(32, 8), 0, stream>>>(w_out, w_outT, 1024, 1024);
  k_qkv_gemm<<<dim3(24, 64), dim3(256), 0, stream>>>(x_bf, w_inT, b_in, qb, kb, vtb);
  k_attn<<<dim3(8, 64), dim3(256), 0, stream>>>(qb, kb, vtb, ao);
  k_out_gemm<<<dim3(8, 64), dim3(256), 0, stream>>>(ao, w_outT, b_out, out);
}

// Round 3
// 277.860 us; speedup vs baseline: 1.9871x; 1.1808x over previous
//
#include <hip/hip_runtime.h>

// ---------- types ----------
typedef float f32x4 __attribute__((ext_vector_type(4)));
typedef __bf16 bf16x8 __attribute__((ext_vector_type(8)));
typedef short s16x8 __attribute__((ext_vector_type(8)));
typedef int i32x4 __attribute__((ext_vector_type(4)));

// f32 -> bf16 round-to-nearest-even
__device__ __forceinline__ unsigned short f2bf(float f) {
  union { float f; unsigned u; } v;
  v.f = f;
  unsigned r = v.u + 0x7FFFu + ((v.u >> 16) & 1u);
  return (unsigned short)(r >> 16);
}

// pack two f32 -> packed bf16x2 (round-half-up via +0x8000, then byte-perm)
__device__ __forceinline__ int pk2bf(float lo, float hi) {
  unsigned a = __builtin_bit_cast(unsigned, lo) + 0x8000u;
  unsigned b = __builtin_bit_cast(unsigned, hi) + 0x8000u;
  return (int)__builtin_amdgcn_perm(b, a, 0x07060302u);
}

#if __has_builtin(__builtin_amdgcn_exp2f)
__device__ __forceinline__ float fexp2(float x) { return __builtin_amdgcn_exp2f(x); }
#else
__device__ __forceinline__ float fexp2(float x) { return exp2f(x); }
#endif

// async 16B global->LDS (wave-uniform base + lane*16; our mappings respect this)
__device__ __forceinline__ void gl_lds16(const void* g, void* l) {
  __builtin_amdgcn_global_load_lds(
      (__attribute__((address_space(1))) void*)g,
      (__attribute__((address_space(3))) void*)l, 16, 0, 0);
}

// ---------- pre-pass kernels ----------
__global__ __launch_bounds__(256) void k_convert_x(const float* __restrict__ in,
                                                   short* __restrict__ out) {
  int i = (blockIdx.x * 256 + threadIdx.x) * 8;
  const float4* p = (const float4*)(in + i);
  float4 a = p[0], b = p[1];
  s16x8 r;
  r[0] = (short)f2bf(a.x); r[1] = (short)f2bf(a.y);
  r[2] = (short)f2bf(a.z); r[3] = (short)f2bf(a.w);
  r[4] = (short)f2bf(b.x); r[5] = (short)f2bf(b.y);
  r[6] = (short)f2bf(b.z); r[7] = (short)f2bf(b.w);
  *(s16x8*)(out + i) = r;
}

// in: [R,C] f32 row-major -> out: [C,R] bf16 row-major
__global__ __launch_bounds__(256) void k_transpose_cvt(const float* __restrict__ in,
                                                       short* __restrict__ out,
                                                       int R, int C) {
  __shared__ short tile[32][33];
  int c0 = blockIdx.x * 32, r0 = blockIdx.y * 32;
  int tx = threadIdx.x, ty = threadIdx.y;
#pragma unroll
  for (int i = 0; i < 32; i += 8)
    tile[ty + i][tx] = (short)f2bf(in[(size_t)(r0 + ty + i) * C + c0 + tx]);
  __syncthreads();
#pragma unroll
  for (int i = 0; i < 32; i += 8)
    out[(size_t)(c0 + ty + i) * R + r0 + tx] = tile[tx][ty + i];
}

// ---------- QKV GEMM: C[8192,3072] = Xbf[8192,1024] @ WinT[3072,1024]^T + b ----------
// epilogue scatters: Q (pre-scaled by scale*log2e), K -> [B,H,L,64] bf16 ; V -> Vt [B,H,64,L] bf16
__global__ __launch_bounds__(256) void k_qkv_gemm(const short* __restrict__ A,
                                                  const short* __restrict__ B,
                                                  const float* __restrict__ bias,
                                                  short* __restrict__ qb,
                                                  short* __restrict__ kb,
                                                  short* __restrict__ vtb) {
  __shared__ short As[128 * 32];
  __shared__ short Bs[128 * 32];
  const int tid = threadIdx.x;
  const int lane = tid & 63;
  const int w = tid >> 6;
  const int g = lane >> 4, c = lane & 15;
  const int m0 = blockIdx.y * 128, n0 = blockIdx.x * 128;
  const int wm = (w >> 1) * 64, wn = (w & 1) * 64;
  f32x4 acc[4][4] = {};
  const int p0 = tid, p1 = tid + 256;
  const int rowA0 = p0 >> 2, logA0 = (p0 & 3) ^ ((p0 >> 3) & 3);
  const int rowA1 = p1 >> 2, logA1 = (p1 & 3) ^ ((p1 >> 3) & 3);
  const short* a0 = A + (size_t)(m0 + rowA0) * 1024 + logA0 * 8;
  const short* a1 = A + (size_t)(m0 + rowA1) * 1024 + logA1 * 8;
  const short* b0 = B + (size_t)(n0 + rowA0) * 1024 + logA0 * 8;
  const short* b1 = B + (size_t)(n0 + rowA1) * 1024 + logA1 * 8;
  short* lA0 = As + p0 * 8; short* lA1 = As + p1 * 8;
  short* lB0 = Bs + p0 * 8; short* lB1 = Bs + p1 * 8;

  for (int k0 = 0; k0 < 1024; k0 += 32) {
    gl_lds16(a0 + k0, lA0);
    gl_lds16(a1 + k0, lA1);
    gl_lds16(b0 + k0, lB0);
    gl_lds16(b1 + k0, lB1);
    __syncthreads();
    bf16x8 af[4], bfr[4];
#pragma unroll
    for (int t = 0; t < 4; t++) {
      int ra = wm + t * 16 + c;
      af[t] = *(const bf16x8*)(As + ra * 32 + (g ^ ((ra >> 1) & 3)) * 8);
      int rb = wn + t * 16 + c;
      bfr[t] = *(const bf16x8*)(Bs + rb * 32 + (g ^ ((rb >> 1) & 3)) * 8);
    }
#pragma unroll
    for (int i = 0; i < 4; i++)
#pragma unroll
      for (int jn = 0; jn < 4; jn++)
        acc[i][jn] = __builtin_amdgcn_mfma_f32_16x16x32_bf16(af[i], bfr[jn], acc[i][jn], 0, 0, 0);
    __syncthreads();
  }

  const int which = n0 >> 10;  // block-uniform: 0=Q 1=K 2=V
  const float qscale = 0.125f * 1.4426950408889634f;  // folded into Q
  if (which == 2) {
    // V^T: 4 consecutive l per lane are contiguous in Vt -> one 8B store each
#pragma unroll
    for (int jn = 0; jn < 4; jn++) {
      const int col = n0 + wn + jn * 16 + c;
      const float bv = bias[col];
      const int cw = col & 1023;
      const int h = cw >> 6, d = cw & 63;
#pragma unroll
      for (int i = 0; i < 4; i++) {
        const int row = m0 + wm + i * 16 + g * 4;  // r=0 row; all 4 in same batch
        const int bb = row >> 11, l0 = row & 2047;
        int lo = pk2bf(acc[i][jn][0] + bv, acc[i][jn][1] + bv);
        int hi = pk2bf(acc[i][jn][2] + bv, acc[i][jn][3] + bv);
        *(int2*)(vtb + (size_t)((bb * 16 + h) * 64 + d) * 2048 + l0) = make_int2(lo, hi);
      }
    }
  } else {
    short* dst = (which == 0) ? qb : kb;
    const float sc = (which == 0) ? qscale : 1.0f;
#pragma unroll
    for (int jn = 0; jn < 4; jn++) {
      const int col = n0 + wn + jn * 16 + c;
      const float bv = bias[col];
      const int cw = col & 1023;
      const int h = cw >> 6, d = cw & 63;
#pragma unroll
      for (int i = 0; i < 4; i++) {
#pragma unroll
        for (int r = 0; r < 4; r++) {
          const int row = m0 + wm + i * 16 + g * 4 + r;
          const int bb = row >> 11, l = row & 2047;
          dst[((size_t)((bb * 16 + h) * 2048 + l) << 6) + d] = (short)f2bf((acc[i][jn][r] + bv) * sc);
        }
      }
    }
  }
}

// stage one 128-key K tile + V^T tile into LDS (async, all 256 threads)
__device__ __forceinline__ void stage_kv(const short* __restrict__ Kt,
                                         const short* __restrict__ Vtt,
                                         short* ksb, short* vsb, int tid) {
#pragma unroll
  for (int t = 0; t < 4; t++) {
    int p = tid + t * 256;
    int krow = p >> 3, kchk = (p & 7) ^ (krow & 7);
    gl_lds16(Kt + (size_t)krow * 64 + kchk * 8, ksb + p * 8);
    int dv = p >> 4, vchk = (p & 15) ^ (dv & 15);
    gl_lds16(Vtt + (size_t)dv * 2048 + vchk * 8, vsb + p * 8);
  }
}

// ---------- flash attention (S^T form, double-buffered K/V) ----------
// 1 block = (bh, paired 128-query tiles (15-pr, pr)): 17 KV tiles, perfectly balanced.
// S^T = mfma(Kfrag, Qfrag); softmax stats per column (2 shuffles);
// P^T -> PV B-frag via quad-routing shuffles; O^T = mfma(Vtfrag, Pfrag).
// K/V tile j+1 prefetched (async global->LDS) right after the barrier, overlapping
// the whole QK+softmax+PV compute of tile j.
__global__ __launch_bounds__(256, 2) void k_attn(const short* __restrict__ Q,
                                                 const short* __restrict__ K,
                                                 const short* __restrict__ Vt,
                                                 short* __restrict__ O) {
  __shared__ short Ks[2][128 * 64];  // 2x16 KB [key][d], 8-chunk XOR swizzle
  __shared__ short Vs[2][64 * 128];  // 2x16 KB [d][key], 16-chunk XOR swizzle
  const int tid = threadIdx.x;
  const int lane = tid & 63;
  const int w = tid >> 6;
  const int quad = lane >> 4, cq = lane & 15;
  const int bh = blockIdx.y;
  const int bb = bh >> 4, h = bh & 15;
  const size_t base = (size_t)bh * (2048 * 64);
  const int pr = blockIdx.x;  // 0..7
  const int sA = cq | (((2 * quad) & 3) << 4);
  const int sB = cq | (((2 * quad + 1) & 3) << 4);

  int tk = 0;  // running tile parity across both phases
  for (int phase = 0; phase < 2; phase++) {
    const int qt = phase ? pr : 15 - pr;
    const int m0 = qt * 128;
    bf16x8 qf[2][2];
#pragma unroll
    for (int mt = 0; mt < 2; mt++)
#pragma unroll
      for (int kd = 0; kd < 2; kd++)
        qf[mt][kd] = *(const bf16x8*)(Q + base +
            (size_t)(m0 + w * 32 + mt * 16 + cq) * 64 + (kd * 4 + quad) * 8);

    if (phase == 0) stage_kv(K + base, Vt + base, Ks[0], Vs[0], tid);

    f32x4 o[2][4] = {};
    float m_run[2] = {-1e30f, -1e30f};
    float l_run[2] = {0.f, 0.f};

    for (int j = 0; j <= qt; j++) {
      const int cur = tk & 1;
      __syncthreads();  // buf[cur] staged; buf[cur^1] fully consumed
      // prefetch next tile into the other buffer (overlaps this tile's compute)
      if (j < qt) {
        stage_kv(K + base + (size_t)(j + 1) * 128 * 64, Vt + base + (j + 1) * 128,
                 Ks[cur ^ 1], Vs[cur ^ 1], tid);
      } else if (phase == 0) {
        stage_kv(K + base, Vt + base, Ks[cur ^ 1], Vs[cur ^ 1], tid);  // phase-1 tile 0
      }
      const short* ks = Ks[cur];
      const short* vs = Vs[cur];

      // S^T[key][q] : per wave 128 keys x 32 queries
      f32x4 s[2][8] = {};
#pragma unroll
      for (int kd = 0; kd < 2; kd++)
#pragma unroll
        for (int nt = 0; nt < 8; nt++) {
          int krow = nt * 16 + cq;
          bf16x8 kf = *(const bf16x8*)(ks + krow * 64 + ((kd * 4 + quad) ^ (krow & 7)) * 8);
          s[0][nt] = __builtin_amdgcn_mfma_f32_16x16x32_bf16(kf, qf[0][kd], s[0][nt], 0, 0, 0);
          s[1][nt] = __builtin_amdgcn_mfma_f32_16x16x32_bf16(kf, qf[1][kd], s[1][nt], 0, 0, 0);
        }

      const bool diag = (j == qt);
      bf16x8 pf[2][4];
#pragma unroll
      for (int mt = 0; mt < 2; mt++) {
        float mx = -1e30f;
        if (diag) {
          int qloc = w * 32 + mt * 16 + cq;
#pragma unroll
          for (int nt = 0; nt < 8; nt++)
#pragma unroll
            for (int r = 0; r < 4; r++) {
              float v = (nt * 16 + quad * 4 + r > qloc) ? -1e30f : s[mt][nt][r];
              s[mt][nt][r] = v;
              mx = fmaxf(mx, v);
            }
        } else {
#pragma unroll
          for (int nt = 0; nt < 8; nt++)
#pragma unroll
            for (int r = 0; r < 4; r++) mx = fmaxf(mx, s[mt][nt][r]);
        }
        mx = fmaxf(mx, __shfl_xor(mx, 16));
        mx = fmaxf(mx, __shfl_xor(mx, 32));
        const float mn = fmaxf(m_run[mt], mx);
        const float alpha = fexp2(m_run[mt] - mn);
        m_run[mt] = mn;
        float lt = 0.f;
#pragma unroll
        for (int nt = 0; nt < 8; nt++)
#pragma unroll
          for (int r = 0; r < 4; r++) {
            float p = fexp2(s[mt][nt][r] - mn);
            s[mt][nt][r] = p;
            lt += p;
          }
        l_run[mt] = l_run[mt] * alpha + lt;
#pragma unroll
        for (int dn = 0; dn < 4; dn++) o[mt][dn] *= alpha;
        // P^T (C-layout) -> PV B-frag: pack pairs, route across quads
#pragma unroll
        for (int kt = 0; kt < 4; kt++) {
          int dA0 = pk2bf(s[mt][2 * kt][0], s[mt][2 * kt][1]);
          int dA1 = pk2bf(s[mt][2 * kt][2], s[mt][2 * kt][3]);
          int dB0 = pk2bf(s[mt][2 * kt + 1][0], s[mt][2 * kt + 1][1]);
          int dB1 = pk2bf(s[mt][2 * kt + 1][2], s[mt][2 * kt + 1][3]);
          i32x4 ow;
          {
            int t0 = __shfl(dA0, sA, 64), t1 = __shfl(dB0, sA, 64);
            ow[0] = (quad < 2) ? t0 : t1;
          }
          {
            int t0 = __shfl(dA1, sA, 64), t1 = __shfl(dB1, sA, 64);
            ow[1] = (quad < 2) ? t0 : t1;
          }
          {
            int t0 = __shfl(dA0, sB, 64), t1 = __shfl(dB0, sB, 64);
            ow[2] = (quad < 2) ? t0 : t1;
          }
          {
            int t0 = __shfl(dA1, sB, 64), t1 = __shfl(dB1, sB, 64);
            ow[3] = (quad < 2) ? t0 : t1;
          }
          pf[mt][kt] = __builtin_bit_cast(bf16x8, ow);
        }
      }

      // O^T += Vt * P  (A=Vt frag, B=P frag)
#pragma unroll
      for (int kt = 0; kt < 4; kt++)
#pragma unroll
        for (int dn = 0; dn < 4; dn++) {
          int drow = dn * 16 + cq;
          bf16x8 vtf = *(const bf16x8*)(vs + drow * 128 + ((kt * 4 + quad) ^ (drow & 15)) * 8);
          o[0][dn] = __builtin_amdgcn_mfma_f32_16x16x32_bf16(vtf, pf[0][kt], o[0][dn], 0, 0, 0);
          o[1][dn] = __builtin_amdgcn_mfma_f32_16x16x32_bf16(vtf, pf[1][kt], o[1][dn], 0, 0, 0);
        }
      tk++;
    }

    // epilogue: reduce l across quads, normalize, pack 4 consecutive d -> 8B store
#pragma unroll
    for (int mt = 0; mt < 2; mt++) {
      float lf = l_run[mt];
      lf += __shfl_xor(lf, 16);
      lf += __shfl_xor(lf, 32);
      const float inv = 1.f / lf;
      const size_t rb = ((size_t)(bb * 2048 + m0 + w * 32 + mt * 16 + cq)) * 1024 + h * 64;
#pragma unroll
      for (int dn = 0; dn < 4; dn++) {
        int d0 = pk2bf(o[mt][dn][0] * inv, o[mt][dn][1] * inv);
        int d1 = pk2bf(o[mt][dn][2] * inv, o[mt][dn][3] * inv);
        *(int2*)(O + rb + dn * 16 + quad * 4) = make_int2(d0, d1);
      }
    }
  }
}

// ---------- out GEMM: out[8192,1024] = AO[8192,1024] @ WoutT[1024,1024]^T + b (fp32 out) ----------
__global__ __launch_bounds__(256) void k_out_gemm(const short* __restrict__ A,
                                                  const short* __restrict__ B,
                                                  const float* __restrict__ bias,
                                                  float* __restrict__ out) {
  __shared__ short As[128 * 32];
  __shared__ short Bs[128 * 32];
  const int tid = threadIdx.x;
  const int lane = tid & 63;
  const int w = tid >> 6;
  const int g = lane >> 4, c = lane & 15;
  const int m0 = blockIdx.y * 128, n0 = blockIdx.x * 128;
  const int wm = (w >> 1) * 64, wn = (w & 1) * 64;
  f32x4 acc[4][4] = {};
  const int p0 = tid, p1 = tid + 256;
  const int rowA0 = p0 >> 2, logA0 = (p0 & 3) ^ ((p0 >> 3) & 3);
  const int rowA1 = p1 >> 2, logA1 = (p1 & 3) ^ ((p1 >> 3) & 3);
  const short* a0 = A + (size_t)(m0 + rowA0) * 1024 + logA0 * 8;
  const short* a1 = A + (size_t)(m0 + rowA1) * 1024 + logA1 * 8;
  const short* b0 = B + (size_t)(n0 + rowA0) * 1024 + logA0 * 8;
  const short* b1 = B + (size_t)(n0 + rowA1) * 1024 + logA1 * 8;
  short* lA0 = As + p0 * 8; short* lA1 = As + p1 * 8;
  short* lB0 = Bs + p0 * 8; short* lB1 = Bs + p1 * 8;

  for (int k0 = 0; k0 < 1024; k0 += 32) {
    gl_lds16(a0 + k0, lA0);
    gl_lds16(a1 + k0, lA1);
    gl_lds16(b0 + k0, lB0);
    gl_lds16(b1 + k0, lB1);
    __syncthreads();
    bf16x8 af[4], bfr[4];
#pragma unroll
    for (int t = 0; t < 4; t++) {
      int ra = wm + t * 16 + c;
      af[t] = *(const bf16x8*)(As + ra * 32 + (g ^ ((ra >> 1) & 3)) * 8);
      int rb = wn + t * 16 + c;
      bfr[t] = *(const bf16x8*)(Bs + rb * 32 + (g ^ ((rb >> 1) & 3)) * 8);
    }
#pragma unroll
    for (int i = 0; i < 4; i++)
#pragma unroll
      for (int jn = 0; jn < 4; jn++)
        acc[i][jn] = __builtin_amdgcn_mfma_f32_16x16x32_bf16(af[i], bfr[jn], acc[i][jn], 0, 0, 0);
    __syncthreads();
  }
#pragma unroll
  for (int jn = 0; jn < 4; jn++) {
    const int col = n0 + wn + jn * 16 + c;
    const float bv = bias[col];
#pragma unroll
    for (int i = 0; i < 4; i++) {
#pragma unroll
      for (int r = 0; r < 4; r++) {
        const int row = m0 + wm + i * 16 + g * 4 + r;
        out[(size_t)row * 1024 + col] = acc[i][jn][r] + bv;
      }
    }
  }
}

// ---------- launch ----------
extern "C" void kernel_launch(void* const* d_in, const int* in_sizes, int n_in,
                              void* d_out, int out_size, void* d_ws, size_t ws_size,
                              hipStream_t stream) {
  const float* x     = (const float*)d_in[0];
  const float* w_in  = (const float*)d_in[1];
  const float* b_in  = (const float*)d_in[2];
  const float* w_out = (const float*)d_in[3];
  const float* b_out = (const float*)d_in[4];
  float* out = (float*)d_out;
  char* ws = (char*)d_ws;
  // workspace layout (needs 88 MB)
  short* x_bf   = (short*)(ws);                      // 16 MB  [8192,1024] bf16
  short* w_inT  = (short*)(ws + (16ull << 20));      //  6 MB  [3072,1024] bf16
  short* w_outT = (short*)(ws + (22ull << 20));      //  2 MB  [1024,1024] bf16
  short* qb     = (short*)(ws + (24ull << 20));      // 16 MB  [B,H,L,64]  bf16 (pre-scaled)
  short* kb     = (short*)(ws + (40ull << 20));      // 16 MB  [B,H,L,64]  bf16
  short* vtb    = (short*)(ws + (56ull << 20));      // 16 MB  [B,H,64,L]  bf16
  short* ao     = (short*)(ws + (72ull << 20));      // 16 MB  [B,L,H*64]  bf16

  k_convert_x<<<dim3(4096), dim3(256), 0, stream>>>(x, x_bf);
  k_transpose_cvt<<<dim3(96, 32), dim3(32, 8), 0, stream>>>(w_in, w_inT, 1024, 3072);
  k_transpose_cvt<<<dim3(32, 32), dim3(32, 8), 0, stream>>>(w_out, w_outT, 1024, 1024);
  k_qkv_gemm<<<dim3(24, 64), dim3(256), 0, stream>>>(x_bf, w_inT, b_in, qb, kb, vtb);
  k_attn<<<dim3(8, 64), dim3(256), 0, stream>>>(qb, kb, vtb, ao);
  k_out_gemm<<<dim3(8, 64), dim3(256), 0, stream>>>(ao, w_outT, b_out, out);
}